// Round 12
// baseline (798.072 us; speedup 1.0000x reference)
//
#include <hip/hip_runtime.h>
#include <math.h>

#define S_LEN 2048
#define DMODEL 512
#define NHEAD 8
#define DH 64
#define FDIM 2048

typedef unsigned short ushort_t;
typedef __attribute__((ext_vector_type(8))) short short8_t;   // 8 bf16 = 4 VGPRs
typedef __attribute__((ext_vector_type(4))) float float4_t;   // MFMA acc

#define MFMA16(a, b, c) __builtin_amdgcn_mfma_f32_16x16x32_bf16(a, b, c, 0, 0, 0)

// ---- output layout (floats) ----
// x_t: [0, 4194304)  x_ids: [4194304, 4202496)  avg: 4202496
// masks: [4202497, 20979713)  loss: 20979713
// masks region doubles as weight-split + rope-table scratch (dead until masks_k).
// NOTE: mask base (out+4202497) is an ODD float offset -> byte addr == 4 mod 16.
// float4 stores are misaligned; mr+1 IS 8B-aligned so float2 on [1..2046] is
// safe with scalar stores for elements 0 and 2047.
// x_t region is NOT pre-copied: layer-0 reads the input x directly and the
// layer-0 Wo-gemm (EPI 1, full M x N coverage) writes every element of it.

// LDS bank-conflict swizzle: logical 16B quad q of row r stored at physical
// quad q ^ ((r>>1)&3). Makes b128 fragment reads (64B row stride) 2-way
// (free, m136) instead of 8-way (2.94x). Bits 1-2 of the row are invariant
// across all uses (tiles are 16-row aligned), so writer/reader agree.

__device__ __forceinline__ ushort_t f2bf(float x) {            // RNE fp32->bf16
    unsigned u = __float_as_uint(x);
    return (ushort_t)((u + 0x7fffu + ((u >> 16) & 1u)) >> 16);
}
__device__ __forceinline__ float bf2f(ushort_t h) {
    return __uint_as_float((unsigned)h << 16);
}
__device__ __forceinline__ float gelu_f(float x) {
    return 0.5f * x * (1.0f + erff(x * 0.70710678118654752440f));
}
__device__ __forceinline__ void gl_lds16(const void* g, void* l) {
    __builtin_amdgcn_global_load_lds(
        (const __attribute__((address_space(1))) void*)g,
        (__attribute__((address_space(3))) void*)l, 16, 0, 0);
}

// ---- DPP 16-lane reductions (pure VALU, no DS pipe) ----
template<int CTRL>
__device__ __forceinline__ float dpp_mov(float x) {
    return __int_as_float(__builtin_amdgcn_mov_dpp(__float_as_int(x), CTRL, 0xF, 0xF, true));
}
__device__ __forceinline__ float dpp_max16(float x) {
    x = fmaxf(x, dpp_mov<0xB1>(x));    // quad_perm [1,0,3,2] : xor 1
    x = fmaxf(x, dpp_mov<0x4E>(x));    // quad_perm [2,3,0,1] : xor 2
    x = fmaxf(x, dpp_mov<0x141>(x));   // row_half_mirror     : xor 4-equiv
    x = fmaxf(x, dpp_mov<0x140>(x));   // row_mirror          : xor 8-equiv
    return x;
}
__device__ __forceinline__ float dpp_sum16(float x) {
    x += dpp_mov<0xB1>(x);
    x += dpp_mov<0x4E>(x);
    x += dpp_mov<0x141>(x);
    x += dpp_mov<0x140>(x);
    return x;
}

// stage a 64x64 bf16 tile (row stride rs ushorts) into LDS [kk][64][32] with
// quad swizzle. LDS dest stays lane-linear (gl_lds16 requirement); the global
// source quad is permuted per lane instead.
__device__ __forceinline__ void stage_tile(const ushort_t* __restrict__ g, int rs,
                                           ushort_t* __restrict__ s, int w, int lane) {
    #pragma unroll
    for (int j = 0; j < 2; ++j) {
        const int c = (w * 2 + j) * 64 + lane;
        const int kk = c >> 8, row = (c >> 2) & 63, q = c & 3;
        const int qs = q ^ ((row >> 1) & 3);
        gl_lds16(g + (size_t)row * rs + kk * 32 + qs * 8, s + c * 8);
    }
}

// ---------------- ids -> out, zero scalar slots (x_t copy elided) -----------
__global__ __launch_bounds__(256) void copy_init_k(const int* __restrict__ x_ids,
                                                   float* __restrict__ out) {
    const int i = blockIdx.x * 256 + threadIdx.x;   // 2048
    const int4 id4 = ((const int4*)x_ids)[i];
    ((float4*)out)[1048576 + i] =
        make_float4((float)id4.x, (float)id4.y, (float)id4.z, (float)id4.w);
    if (i == 0) { out[4202496] = 0.0f; out[20979713] = 0.0f; }
}

// ---------------- RoPE cos/sin table: tab[s*32+f] = (cos, sin) --------------
__global__ __launch_bounds__(256) void rope_tab_k(float2* __restrict__ tab) {
    const int i = blockIdx.x * 256 + threadIdx.x;   // 65536
    const int s = i >> 5, f = i & 31;
    float inv = powf(10000.0f, -(float)f * (1.0f / 32.0f));
    float sn, cs;
    sincosf((float)s * inv, &sn, &cs);
    tab[i] = make_float2(cs, sn);
}

// ---------------- ALL weights transpose + split, one dispatch ----------------
__global__ __launch_bounds__(256) void tsplit_all_k(const float* __restrict__ Wq,
                                                    const float* __restrict__ Wk,
                                                    const float* __restrict__ Wv,
                                                    const float* __restrict__ Wo,
                                                    const float* __restrict__ W1,
                                                    const float* __restrict__ W2,
                                                    ushort_t* __restrict__ wbuf) {
    __shared__ float T[32][33];
    const int bid = blockIdx.x;
    const int l = bid / 3072;
    const int r = bid % 3072;
    ushort_t* lb = wbuf + (size_t)l * 6291456;
    const float* W; ushort_t* Thi; ushort_t* Tlo; int K, N, ntn, rr;
    if (r < 768) {
        const int which = r >> 8; rr = r & 255;
        W = (which == 0 ? Wq : which == 1 ? Wk : Wv) + (size_t)l * 262144;
        Thi = lb + which * 262144; Tlo = lb + 786432 + which * 262144;
        K = 512; N = 512; ntn = 16;
    } else if (r < 1024) {
        rr = r - 768; W = Wo + (size_t)l * 262144;
        Thi = lb + 1572864; Tlo = lb + 1835008; K = 512; N = 512; ntn = 16;
    } else if (r < 2048) {
        rr = r - 1024; W = W1 + (size_t)l * 1048576;
        Thi = lb + 2097152; Tlo = lb + 3145728; K = 512; N = 2048; ntn = 64;
    } else {
        rr = r - 2048; W = W2 + (size_t)l * 1048576;
        Thi = lb + 4194304; Tlo = lb + 5242880; K = 2048; N = 512; ntn = 16;
    }
    const int n0 = (rr % ntn) * 32, k0 = (rr / ntn) * 32;
    const int tx = threadIdx.x & 31, ty = threadIdx.x >> 5;
    #pragma unroll
    for (int i = 0; i < 4; ++i)
        T[ty + 8 * i][tx] = W[(size_t)(k0 + ty + 8 * i) * N + n0 + tx];
    __syncthreads();
    #pragma unroll
    for (int i = 0; i < 4; ++i) {
        const int n = ty + 8 * i;
        float x = T[tx][n];
        ushort_t hi = f2bf(x);
        Thi[(size_t)(n0 + n) * K + k0 + tx] = hi;
        Tlo[(size_t)(n0 + n) * K + k0 + tx] = f2bf(x - bf2f(hi));
    }
}

// ---------------- RMSNorm -> hi/lo bf16 split --------------------------------
// Block->row remap (b&7)*1024 + (b>>3): writer-XCD == consumer-gemm-XCD.
__global__ __launch_bounds__(256) void rmsnorm_split_k(const float* __restrict__ x,
                                                       const float* __restrict__ w,
                                                       ushort_t* __restrict__ hhi,
                                                       ushort_t* __restrict__ hlo) {
    __shared__ float red[4];
    const int tid = threadIdx.x;
    const int b = blockIdx.x;
    const size_t row = (size_t)((b & 7) * 1024 + (b >> 3));
    const float* xr = x + row * DMODEL;
    float2 v = *(const float2*)(xr + tid * 2);
    float ss = v.x * v.x + v.y * v.y;
    #pragma unroll
    for (int off = 32; off; off >>= 1) ss += __shfl_down(ss, off);
    if ((tid & 63) == 0) red[tid >> 6] = ss;
    __syncthreads();
    float tot = red[0] + red[1] + red[2] + red[3];
    float rs = 1.0f / sqrtf(tot * (1.0f / 512.0f) + 1e-6f);
    float2 wv = *(const float2*)(w + tid * 2);
    float y0 = v.x * rs * wv.x, y1 = v.y * rs * wv.y;
    ushort_t h0 = f2bf(y0), h1 = f2bf(y1);
    ushort_t l0 = f2bf(y0 - bf2f(h0)), l1 = f2bf(y1 - bf2f(h1));
    *(unsigned*)(hhi + row * DMODEL + tid * 2) = ((unsigned)h1 << 16) | h0;
    *(unsigned*)(hlo + row * DMODEL + tid * 2) = ((unsigned)l1 << 16) | l0;
}

// ---------------- bf16x3 split MFMA GEMM (swizzled LDS, pipelined) ----------
// 1-D grid N/TN * 64 blocks, XCD-grouped (id&7 = XCD owns 8 bm rows).
// TN=128: 2-buffer, 1-ahead, __syncthreads per K-step.
// TN=64:  3-buffer, 2-ahead, counted vmcnt (T4): stage(t+2) issued during
//   compute(t), barrier waits vmcnt(LPS) so stage(t+1)'s 6 loads stay in
//   flight across the barrier. Raw s_barrier does NOT auto-drain vmcnt;
//   lgkmcnt(0) orders prior ds_reads before the 3rd buffer is overwritten.
//   Used for Wo/W2 AND (r11) W1: same-shape W2 runs ~7% faster per FLOP in
//   this config than the TN=128 2-buf form (deeper pipeline, finer grid).
template<int EPI, int TN>
__global__ __launch_bounds__(256) void gemm_s(const ushort_t* __restrict__ Ahi,
                                              const ushort_t* __restrict__ Alo,
                                              const ushort_t* __restrict__ Bhi,
                                              const ushort_t* __restrict__ Blo,
                                              int K, int N,
                                              float* __restrict__ C,
                                              const float* __restrict__ Cin,
                                              ushort_t* __restrict__ Chi,
                                              ushort_t* __restrict__ Clo,
                                              ushort_t* __restrict__ oqh,
                                              ushort_t* __restrict__ oql,
                                              ushort_t* __restrict__ okh,
                                              ushort_t* __restrict__ okl,
                                              ushort_t* __restrict__ ovh,
                                              const float2* __restrict__ rtab) {
    constexpr int MT = (TN == 128) ? 4 : 2;        // m-tiles per wave
    constexpr int NBUF = (TN == 64) ? 3 : 2;       // pipeline depth
    constexpr int LPS = (TN == 64) ? 6 : 8;        // gl_lds per thread per stage
    __shared__ __align__(16) ushort_t sAhi[NBUF][4096], sAlo[NBUF][4096];
    __shared__ __align__(16) ushort_t sBhi[NBUF][TN * 32], sBlo[NBUF][TN * 32];
    const int tid = threadIdx.x;
    const int lane = tid & 63, w = tid >> 6;
    const int wm = (TN == 128) ? (w >> 1) : w;
    const int wn = (TN == 128) ? (w & 1) : 0;
    const int nbn = N / TN;
    const int id = blockIdx.x;
    const int jj = id >> 3;
    const int bm = (id & 7) * 8 + jj / nbn;        // XCD-grouped bm
    const int bn = jj % nbn;
    const int sm = lane >> 2;                       // staging row in 16-chunk
    const int sk = ((lane & 3) ^ ((sm >> 1) & 3)) * 8;  // swizzled global quad
    const int fr = lane & 15;
    const int fq = lane >> 4;
    const int fko = (fq ^ ((fr >> 1) & 3)) * 8;     // swizzled frag k-offset

    auto stage = [&](int buf, int kt) {
        #pragma unroll
        for (int j = 0; j < 2; ++j) {              // A: 8 chunks x 16 rows
            const int chunk = w * 2 + j;
            const int mr = chunk * 16 + sm;
            const size_t ga = (size_t)(bm * 128 + mr) * K + kt + sk;
            gl_lds16(Ahi + ga, &sAhi[buf][chunk * 512]);
            gl_lds16(Alo + ga, &sAlo[buf][chunk * 512]);
        }
        #pragma unroll
        for (int j = 0; j < TN / 64; ++j) {        // B: TN/16 chunks
            const int chunk = w * (TN / 64) + j;
            const int mr = chunk * 16 + sm;
            const size_t gb = (size_t)(bn * TN + mr) * K + kt + sk;
            gl_lds16(Bhi + gb, &sBhi[buf][chunk * 512]);
            gl_lds16(Blo + gb, &sBlo[buf][chunk * 512]);
        }
    };

    float4_t acc[MT][4] = {};

    if (NBUF == 3) {
        stage(0, 0);
        if (32 < K) stage(1, 32);
    } else {
        stage(0, 0);
    }
    int cur = 0;
    for (int kt = 0; kt < K; kt += 32) {
        if (NBUF == 2) {
            __syncthreads();                       // buf[cur] ready; prior reads done
            if (kt + 32 < K) stage(cur ^ 1, kt + 32);
        } else {
            // retire stage(t) only; stage(t+1) (6 loads) stays in flight
            if (kt + 32 < K)
                asm volatile("s_waitcnt vmcnt(%0) lgkmcnt(0)" :: "i"(LPS) : "memory");
            else
                asm volatile("s_waitcnt vmcnt(0) lgkmcnt(0)" ::: "memory");
            __builtin_amdgcn_s_barrier();
            if (kt + 64 < K) stage((cur + 2) % 3, kt + 64);
        }
        short8_t ah[MT], al[MT], bh[4], bl[4];
        #pragma unroll
        for (int t = 0; t < MT; ++t) {
            const int ao = (wm * (MT * 16) + t * 16 + fr) * 32 + fko;
            ah[t] = *(const short8_t*)&sAhi[cur][ao];
            al[t] = *(const short8_t*)&sAlo[cur][ao];
        }
        #pragma unroll
        for (int t = 0; t < 4; ++t) {
            const int bo = (wn * 64 + t * 16 + fr) * 32 + fko;
            bh[t] = *(const short8_t*)&sBhi[cur][bo];
            bl[t] = *(const short8_t*)&sBlo[cur][bo];
        }
        #pragma unroll
        for (int tm = 0; tm < MT; ++tm)
            #pragma unroll
            for (int tn = 0; tn < 4; ++tn) {
                acc[tm][tn] = MFMA16(ah[tm], bh[tn], acc[tm][tn]);
                acc[tm][tn] = MFMA16(al[tm], bh[tn], acc[tm][tn]);
                acc[tm][tn] = MFMA16(ah[tm], bl[tn], acc[tm][tn]);
            }
        cur = (cur + 1) % NBUF;
    }

    // epilogue: C/D layout col = lane&15, row = (lane>>4)*4 + reg  [m89/m91]
    if (EPI == 0) {
        const int cb = bn * 128 + wn * 64;         // one head per wave-half
        const int mat = cb >> 9;                   // 0=q 1=k 2=v
        const int hh = (cb >> 6) & 7;
        #pragma unroll
        for (int tm = 0; tm < MT; ++tm) {
            #pragma unroll
            for (int r = 0; r < 4; ++r) {
                const int mg = bm * 128 + wm * (MT * 16) + tm * 16 + fq * 4 + r;
                const int b = mg >> 11, s = mg & 2047;
                const int bhh = b * NHEAD + hh;
                if (mat < 2) {
                    ushort_t* dhi = (mat == 0) ? oqh : okh;
                    ushort_t* dlo = (mat == 0) ? oql : okl;
                    const size_t base = ((size_t)bhh * S_LEN + s) * DH;
                    #pragma unroll
                    for (int tn = 0; tn < 2; ++tn) {
                        const int d1 = tn * 16 + fr;
                        const float v1 = acc[tm][tn][r], v2 = acc[tm][tn + 2][r];
                        const float2 t = rtab[s * 32 + d1];
                        float r1 = v1 * t.x - v2 * t.y;
                        float r2 = v1 * t.y + v2 * t.x;
                        if (mat == 0) { r1 *= 0.125f; r2 *= 0.125f; } // fold 1/sqrt(Dh)
                        ushort_t h1 = f2bf(r1), h2 = f2bf(r2);
                        dhi[base + d1]      = h1;
                        dlo[base + d1]      = f2bf(r1 - bf2f(h1));
                        dhi[base + d1 + 32] = h2;
                        dlo[base + d1 + 32] = f2bf(r2 - bf2f(h2));
                    }
                } else {
                    #pragma unroll
                    for (int tn = 0; tn < 4; ++tn) {
                        const int d = tn * 16 + fr;
                        const size_t off = ((size_t)bhh * DH + d) * S_LEN + s;
                        ovh[off] = f2bf(acc[tm][tn][r]);
                    }
                }
            }
        }
    } else {
        #pragma unroll
        for (int tm = 0; tm < MT; ++tm) {
            #pragma unroll
            for (int tn = 0; tn < 4; ++tn) {
                const int cb = bn * TN + wn * 64 + tn * 16;
                #pragma unroll
                for (int r = 0; r < 4; ++r) {
                    const int mg = bm * 128 + wm * (MT * 16) + tm * 16 + fq * 4 + r;
                    const float val = acc[tm][tn][r];
                    const size_t off = (size_t)mg * N + cb + fr;
                    if (EPI == 1) {
                        C[off] = Cin[off] + val;
                    } else {
                        const float g = gelu_f(val);
                        const ushort_t hi = f2bf(g);
                        Chi[off] = hi;
                        Clo[off] = f2bf(g - bf2f(hi));
                    }
                }
            }
        }
    }
}

// ---------------- MFMA causal flash attention (swizzled LDS) -----------------
// 1-D grid 1024: bh = blockIdx&31 (XCD-pinned K/V: id&7 = bh&7), qt heavy-
// first (31 - id>>5). 40KB LDS -> 4 blocks/CU: co-resident blocks fill both
// pipes' idle slots (m114 inter-block overlap).
// Vh double-buffered (staged at top of step t for t+1); Kh AND Kl SINGLE-
// buffered: both are QK-phase-only reads, so they're staged at the mid-step
// barrier after softmax (all QK(t) reads retired by then) and drained by the
// next top barrier before QK(t+1) reads them.
// Softmax reductions use DPP (VALU) instead of shfl_xor (ds_bpermute).
__global__ __launch_bounds__(256) void attn_k(const ushort_t* __restrict__ qhi,
                                              const ushort_t* __restrict__ qlo,
                                              const ushort_t* __restrict__ khi,
                                              const ushort_t* __restrict__ klo,
                                              const ushort_t* __restrict__ vthi,
                                              ushort_t* __restrict__ Ohi,
                                              ushort_t* __restrict__ Olo) {
    __shared__ __align__(16) ushort_t sVh[2][4096];
    __shared__ __align__(16) ushort_t sKh[4096], sKl[4096], sPh[4096];
    const int tid = threadIdx.x, lane = tid & 63, w = tid >> 6;
    const int fr = lane & 15, fq = lane >> 4;
    const int fko = (fq ^ ((fr >> 1) & 3)) * 8;     // swizzled frag k-offset
    const int bidx = blockIdx.x;
    const int bh = bidx & 31;
    const int qt = 31 - (bidx >> 5);                // heavy blocks dispatch first

    short8_t qfh[2], qfl[2];
    {
        const size_t base = ((size_t)bh * S_LEN + qt * 64 + w * 16 + fr) * DH + fq * 8;
        qfh[0] = *(const short8_t*)(qhi + base);
        qfh[1] = *(const short8_t*)(qhi + base + 32);
        qfl[0] = *(const short8_t*)(qlo + base);
        qfl[1] = *(const short8_t*)(qlo + base + 32);
    }

    float m_r[4], l_r[4];
    float4_t oacc[4] = {};
    #pragma unroll
    for (int r = 0; r < 4; ++r) { m_r[r] = -INFINITY; l_r[r] = 0.0f; }

    // prologue: stage everything for step 0
    stage_tile(khi + (size_t)bh * S_LEN * DH, 64, sKh, w, lane);
    stage_tile(klo + (size_t)bh * S_LEN * DH, 64, sKl, w, lane);
    stage_tile(vthi + (size_t)bh * DH * S_LEN, S_LEN, sVh[0], w, lane);
    int cur = 0;

    for (int kt = 0; kt <= qt; ++kt) {
        const bool diag = (kt == qt);
        __syncthreads();        // vmcnt(0): sVh[cur]+sKh+sKl visible; prior reads done
        if (kt < qt) {          // prefetch Vh(t+1); Kh/Kl(t+1) staged at mid-barrier
            const size_t vo = (size_t)bh * DH * S_LEN + (kt + 1) * 64;
            stage_tile(vthi + vo, S_LEN, sVh[cur ^ 1], w, lane);
        }

        float4_t sacc[4] = {};
        __builtin_amdgcn_s_setprio(1);
        #pragma unroll
        for (int kk = 0; kk < 2; ++kk) {
            #pragma unroll
            for (int n = 0; n < 4; ++n) {
                const int bb = kk * 2048 + (n * 16 + fr) * 32 + fko;
                short8_t kh2 = *(const short8_t*)&sKh[bb];
                short8_t kl2 = *(const short8_t*)&sKl[bb];
                sacc[n] = MFMA16(qfh[kk], kh2, sacc[n]);
                sacc[n] = MFMA16(qfl[kk], kh2, sacc[n]);
                sacc[n] = MFMA16(qfh[kk], kl2, sacc[n]);
            }
        }
        __builtin_amdgcn_s_setprio(0);

        #pragma unroll
        for (int r = 0; r < 4; ++r) {
            const int qrow = w * 16 + fq * 4 + r;
            const int psw = (qrow >> 1) & 3;       // P write swizzle
            float sv[4], mx = -INFINITY;
            #pragma unroll
            for (int n = 0; n < 4; ++n) {
                sv[n] = sacc[n][r];
                if (diag && (n * 16 + fr) > qrow) sv[n] = -1e30f;
                mx = fmaxf(mx, sv[n]);
            }
            mx = dpp_max16(mx);
            const float mn = fmaxf(m_r[r], mx);
            const float alp = __expf(m_r[r] - mn);
            m_r[r] = mn;
            float ls = 0.0f;
            #pragma unroll
            for (int n = 0; n < 4; ++n) {
                const float pv = __expf(sv[n] - mn);
                const int c0 = (n & 1) * 16 + fr;
                const int idx = (n >> 1) * 2048 + qrow * 32 + ((c0 >> 3) ^ psw) * 8 + (c0 & 7);
                sPh[idx] = f2bf(pv);
                ls += pv;
            }
            ls = dpp_sum16(ls);
            l_r[r] = alp * l_r[r] + ls;
            #pragma unroll
            for (int n = 0; n < 4; ++n) oacc[n][r] *= alp;
        }

        if (kt < qt) {
            __syncthreads();    // all waves' sKh/sKl QK-reads retired; safe to overwrite
            const size_t ko = ((size_t)bh * S_LEN + (kt + 1) * 64) * DH;
            stage_tile(khi + ko, 64, sKh, w, lane);
            stage_tile(klo + ko, 64, sKl, w, lane);
        }

        __builtin_amdgcn_s_setprio(1);
        #pragma unroll
        for (int kkj = 0; kkj < 2; ++kkj) {
            short8_t ph = *(const short8_t*)&sPh[kkj * 2048 + (w * 16 + fr) * 32 + fko];
            #pragma unroll
            for (int n = 0; n < 4; ++n) {
                short8_t vh = *(const short8_t*)&sVh[cur][kkj * 2048 + (n * 16 + fr) * 32 + fko];
                oacc[n] = MFMA16(ph, vh, oacc[n]);
            }
        }
        __builtin_amdgcn_s_setprio(0);
        cur ^= 1;
    }

    const int b = bh >> 3, hh = bh & 7;
    #pragma unroll
    for (int r = 0; r < 4; ++r) {
        const float inv_l = 1.0f / l_r[r];
        const int s = qt * 64 + w * 16 + fq * 4 + r;
        const size_t base = ((size_t)b * S_LEN + s) * DMODEL + hh * DH;
        #pragma unroll
        for (int n = 0; n < 4; ++n) {
            const float y = oacc[n][r] * inv_l;
            const ushort_t h = f2bf(y);
            Ohi[base + n * 16 + fr] = h;
            Olo[base + n * 16 + fr] = f2bf(y - bf2f(h));
        }
    }
}

// ---------------- head: logits -> sigmoid -> probs (no atomics) -------------
__global__ __launch_bounds__(256) void head_k(const float* __restrict__ x,
                                              const float* __restrict__ w,
                                              const float* __restrict__ b,
                                              float* __restrict__ probs) {
    const int tid = threadIdx.x;
    const int lane = tid & 63;
    const size_t row = (size_t)blockIdx.x * 4 + (tid >> 6);
    const float* xr = x + row * DMODEL;
    float acc = 0.0f;
    #pragma unroll
    for (int i = 0; i < 8; ++i) acc += xr[lane + i * 64] * w[lane + i * 64];
    #pragma unroll
    for (int off = 32; off; off >>= 1) acc += __shfl_down(acc, off);
    if (lane == 0)
        probs[row] = 1.0f / (1.0f + expf(-(acc + b[0])));
}

// ---------------- chunk id scan (binary lifting) + loss reduction ------------
__global__ __launch_bounds__(256) void chunk_k(const float* __restrict__ probs,
                                               int* __restrict__ ids,
                                               float* __restrict__ avg_out,
                                               float* __restrict__ loss_out) {
    __shared__ ushort_t nxA[2052], nxB[2052];
    __shared__ ushort_t lift[10][2052];
    __shared__ float lred[4];
    __shared__ int anyf;
    const int b = blockIdx.x, tid = threadIdx.x;
    const float* pr = probs + (size_t)b * S_LEN;
    if (tid == 0) anyf = 0;
    __syncthreads();
    int loc = 0;
    float lsum = 0.0f;
    for (int t = tid; t < S_LEN; t += 256) {
        const float p = pr[t];
        loc |= (p > 0.5f) ? 1 : 0;
        lsum += p;
    }
    if (loc) atomicOr(&anyf, 1);
    #pragma unroll
    for (int off = 32; off; off >>= 1) lsum += __shfl_down(lsum, off);
    if ((tid & 63) == 0) lred[tid >> 6] = lsum;
    __syncthreads();
    if (tid == 0)
        atomicAdd(loss_out, (lred[0] + lred[1] + lred[2] + lred[3]) * 0.25f);
    const int any = anyf;
    for (int i = tid; i <= S_LEN; i += 256) {
        const bool he = any ? (i >= 1 && pr[i - 1] > 0.5f) : (i == S_LEN - 1);
        nxA[i] = he ? (ushort_t)i : (ushort_t)(S_LEN + 1);
    }
    __syncthreads();
    ushort_t* src = nxA;
    ushort_t* dst = nxB;
    for (int d = 1; d <= 2048; d <<= 1) {
        for (int i = tid; i <= S_LEN; i += 256) {
            ushort_t v = src[i];
            if (i + d <= S_LEN) { ushort_t u2 = src[i + d]; v = u2 < v ? u2 : v; }
            dst[i] = v;
        }
        __syncthreads();
        ushort_t* tmp = src; src = dst; dst = tmp;
    }
    for (int t = tid; t < S_LEN; t += 256) {
        int cap = t + 16; if (cap > S_LEN) cap = S_LEN;
        int e = src[t + 1];
        if (e > cap) e = cap;
        if (e - t < 3) { e = t + 3; if (e > S_LEN) e = S_LEN; }
        lift[0][t] = (ushort_t)e;
    }
    if (tid == 0) lift[0][S_LEN] = (ushort_t)S_LEN;
    __syncthreads();
    for (int j = 1; j < 10; ++j) {
        for (int t = tid; t <= S_LEN; t += 256)
            lift[j][t] = lift[j - 1][lift[j - 1][t]];
        __syncthreads();
    }
    for (int t = tid; t < S_LEN; t += 256) {
        int pos = 0, cid = 0;
        #pragma unroll
        for (int j = 9; j >= 0; --j) {
            const int p2 = lift[j][pos];
            if (p2 <= t) { pos = p2; cid += (1 << j); }
        }
        ids[(size_t)b * S_LEN + t] = cid;
        if (t == S_LEN - 1) atomicAdd(avg_out, 512.0f / (float)(cid + 1));
    }
}

// ---------------- masks ------------------------------------------------------
// Row base is odd (4-byte aligned only), but mr+1 is 8B-aligned: elements 0
// and 2047 stored scalar, [1..2046] as 1023 aligned float2 pairs.
__global__ __launch_bounds__(256) void masks_k(const int* __restrict__ ids,
                                               float* __restrict__ mask) {
    const int bq = blockIdx.x;
    const int b = bq >> 11;
    const int myid = ids[bq];
    const int* idr = ids + (size_t)b * S_LEN;
    float* mr = mask + (size_t)bq * S_LEN;
    if (threadIdx.x == 0) {
        mr[0] = (idr[0] == myid) ? 1.0f : 0.0f;
        mr[2047] = (idr[2047] == myid) ? 1.0f : 0.0f;
    }
    float2* m2 = (float2*)(mr + 1);
    for (int k = threadIdx.x; k < 1023; k += 256) {
        const int i0 = idr[1 + 2 * k], i1 = idr[2 + 2 * k];
        m2[k] = make_float2(i0 == myid ? 1.0f : 0.0f, i1 == myid ? 1.0f : 0.0f);
    }
}

extern "C" void kernel_launch(void* const* d_in, const int* in_sizes, int n_in,
                              void* d_out, int out_size, void* d_ws, size_t ws_size,
                              hipStream_t stream) {
    (void)in_sizes; (void)n_in; (void)out_size; (void)ws_size;
    const float* x      = (const float*)d_in[0];
    const int*   x_ids  = (const int*)d_in[1];
    const float* ln1    = (const float*)d_in[2];
    const float* Wq     = (const float*)d_in[3];
    const float* Wk     = (const float*)d_in[4];
    const float* Wv     = (const float*)d_in[5];
    const float* Wo     = (const float*)d_in[6];
    const float* ln2    = (const float*)d_in[7];
    const float* W1     = (const float*)d_in[8];
    const float* W2     = (const float*)d_in[9];
    const float* head_w = (const float*)d_in[10];
    const float* head_b = (const float*)d_in[11];

    float* out = (float*)d_out;
    ushort_t* u = (ushort_t*)d_ws;
    ushort_t* qh   = u;                 // [32 bh][2048 s][64 d] roped q (x 1/8) hi
    ushort_t* ql   = u + 4194304;
    ushort_t* kh   = u + 8388608;       // roped k
    ushort_t* kl   = u + 12582912;
    ushort_t* vth  = u + 16777216;      // v transposed hi [32 bh][64 d][2048 s]
    ushort_t* ohi  = u + 25165824;      // attn out [8192][512]
    ushort_t* olo  = u + 29360128;
    ushort_t* hhi  = u + 33554432;      // rmsnorm out [8192][512]
    ushort_t* hlo  = u + 37748736;
    ushort_t* ffhi = u;                 // [8192][2048]; overlays q..k (dead after attn)
    ushort_t* fflo = u + 16777216;      // overlays vt..o (dead after Wo gemm)
    float*    probs = (float*)(u + 41943040);
    int*      ids   = (int*)(u + 41943040 + 16384);
    // weight-split (both layers) + rope table in out's mask region:
    ushort_t* wbuf     = (ushort_t*)(out + 4202512);   // 16B-aligned
    float2*   rope_tab = (float2*)(wbuf + 12582912);   // [2048][32] (cos,sin)
    float* xbuf = out;

    copy_init_k<<<8, 256, 0, stream>>>(x_ids, out);
    rope_tab_k<<<256, 256, 0, stream>>>(rope_tab);
    tsplit_all_k<<<6144, 256, 0, stream>>>(Wq, Wk, Wv, Wo, W1, W2, wbuf);

    for (int l = 0; l < 2; ++l) {
        ushort_t* lb = wbuf + (size_t)l * 6291456;
        ushort_t* qkvT_hi = lb;
        ushort_t* qkvT_lo = lb + 786432;
        ushort_t* woT_hi  = lb + 1572864;
        ushort_t* woT_lo  = lb + 1835008;
        ushort_t* w1T_hi  = lb + 2097152;
        ushort_t* w1T_lo  = lb + 3145728;
        ushort_t* w2T_hi  = lb + 4194304;
        ushort_t* w2T_lo  = lb + 5242880;
        // layer 0 reads the residual stream straight from the input buffer;
        // the Wo-gemm (full M x N coverage) then writes all of xbuf.
        const float* xin = (l == 0) ? x : xbuf;

        rmsnorm_split_k<<<8192, 256, 0, stream>>>(xin, ln1 + l * DMODEL, hhi, hlo);
        gemm_s<0, 128><<<768, 256, 0, stream>>>(hhi, hlo, qkvT_hi, qkvT_lo, 512, 1536,
                                                nullptr, nullptr, nullptr, nullptr,
                                                qh, ql, kh, kl, vth, rope_tab);
        attn_k<<<1024, 256, 0, stream>>>(qh, ql, kh, kl, vth, ohi, olo);
        gemm_s<1, 64><<<512, 256, 0, stream>>>(ohi, olo, woT_hi, woT_lo, 512, 512,
                                               xbuf, xin, nullptr, nullptr,
                                               nullptr, nullptr, nullptr, nullptr, nullptr, nullptr);
        rmsnorm_split_k<<<8192, 256, 0, stream>>>(xbuf, ln2 + l * DMODEL, hhi, hlo);
        gemm_s<2, 64><<<2048, 256, 0, stream>>>(hhi, hlo, w1T_hi, w1T_lo, 512, 2048,
                                                nullptr, nullptr, ffhi, fflo,
                                                nullptr, nullptr, nullptr, nullptr, nullptr, nullptr);
        gemm_s<1, 64><<<512, 256, 0, stream>>>(ffhi, fflo, w2T_hi, w2T_lo, 2048, 512,
                                               xbuf, xbuf, nullptr, nullptr,
                                               nullptr, nullptr, nullptr, nullptr, nullptr, nullptr);
    }

    head_k<<<2048, 256, 0, stream>>>(xbuf, head_w, head_b, probs);
    chunk_k<<<4, 256, 0, stream>>>(probs, ids, out + 4202496, out + 20979713);
    masks_k<<<8192, 256, 0, stream>>>(ids, out + 4202497);
}

// Round 13
// 762.495 us; speedup vs baseline: 1.0467x; 1.0467x over previous
//
#include <hip/hip_runtime.h>
#include <math.h>

#define S_LEN 2048
#define DMODEL 512
#define NHEAD 8
#define DH 64
#define FDIM 2048

typedef unsigned short ushort_t;
typedef __attribute__((ext_vector_type(8))) short short8_t;   // 8 bf16 = 4 VGPRs
typedef __attribute__((ext_vector_type(4))) float float4_t;   // MFMA acc

#define MFMA16(a, b, c) __builtin_amdgcn_mfma_f32_16x16x32_bf16(a, b, c, 0, 0, 0)

// ---- output layout (floats) ----
// x_t: [0, 4194304)  x_ids: [4194304, 4202496)  avg: 4202496
// masks: [4202497, 20979713)  loss: 20979713
// masks region doubles as weight-split + rope-table scratch (dead until masks_k).
// NOTE: mask base (out+4202497) is an ODD float offset -> byte addr == 4 mod 16.
// float4 stores are misaligned; mr+1 IS 8B-aligned so float2 on [1..2046] is
// safe with scalar stores for elements 0 and 2047.
// x_t region is NOT pre-copied: layer-0 reads the input x directly and the
// layer-0 Wo-gemm (EPI 1, full M x N coverage) writes every element of it.
// TILE LESSON (r11): W1 at TN=64 regressed (FETCH 45->75MB, 75->93us) —
// smaller tiles halve B-reuse and double A-strip sharing; reuse > pipeline
// depth for these shapes. W1 stays TN=128.

// LDS bank-conflict swizzle: logical 16B quad q of row r stored at physical
// quad q ^ ((r>>1)&3). Makes b128 fragment reads (64B row stride) 2-way
// (free, m136) instead of 8-way (2.94x). Bits 1-2 of the row are invariant
// across all uses (tiles are 16-row aligned), so writer/reader agree.

__device__ __forceinline__ ushort_t f2bf(float x) {            // RNE fp32->bf16
    unsigned u = __float_as_uint(x);
    return (ushort_t)((u + 0x7fffu + ((u >> 16) & 1u)) >> 16);
}
__device__ __forceinline__ float bf2f(ushort_t h) {
    return __uint_as_float((unsigned)h << 16);
}
__device__ __forceinline__ float gelu_f(float x) {
    return 0.5f * x * (1.0f + erff(x * 0.70710678118654752440f));
}
__device__ __forceinline__ void gl_lds16(const void* g, void* l) {
    __builtin_amdgcn_global_load_lds(
        (const __attribute__((address_space(1))) void*)g,
        (__attribute__((address_space(3))) void*)l, 16, 0, 0);
}

// ---- DPP 16-lane reductions (pure VALU, no DS pipe) ----
template<int CTRL>
__device__ __forceinline__ float dpp_mov(float x) {
    return __int_as_float(__builtin_amdgcn_mov_dpp(__float_as_int(x), CTRL, 0xF, 0xF, true));
}
__device__ __forceinline__ float dpp_max16(float x) {
    x = fmaxf(x, dpp_mov<0xB1>(x));    // quad_perm [1,0,3,2] : xor 1
    x = fmaxf(x, dpp_mov<0x4E>(x));    // quad_perm [2,3,0,1] : xor 2
    x = fmaxf(x, dpp_mov<0x141>(x));   // row_half_mirror     : xor 4-equiv
    x = fmaxf(x, dpp_mov<0x140>(x));   // row_mirror          : xor 8-equiv
    return x;
}
__device__ __forceinline__ float dpp_sum16(float x) {
    x += dpp_mov<0xB1>(x);
    x += dpp_mov<0x4E>(x);
    x += dpp_mov<0x141>(x);
    x += dpp_mov<0x140>(x);
    return x;
}

// stage a 64x64 bf16 tile (row stride rs ushorts) into LDS [kk][64][32] with
// quad swizzle. LDS dest stays lane-linear (gl_lds16 requirement); the global
// source quad is permuted per lane instead.
__device__ __forceinline__ void stage_tile(const ushort_t* __restrict__ g, int rs,
                                           ushort_t* __restrict__ s, int w, int lane) {
    #pragma unroll
    for (int j = 0; j < 2; ++j) {
        const int c = (w * 2 + j) * 64 + lane;
        const int kk = c >> 8, row = (c >> 2) & 63, q = c & 3;
        const int qs = q ^ ((row >> 1) & 3);
        gl_lds16(g + (size_t)row * rs + kk * 32 + qs * 8, s + c * 8);
    }
}

// ---------------- ids -> out, zero scalar slots (x_t copy elided) -----------
__global__ __launch_bounds__(256) void copy_init_k(const int* __restrict__ x_ids,
                                                   float* __restrict__ out) {
    const int i = blockIdx.x * 256 + threadIdx.x;   // 2048
    const int4 id4 = ((const int4*)x_ids)[i];
    ((float4*)out)[1048576 + i] =
        make_float4((float)id4.x, (float)id4.y, (float)id4.z, (float)id4.w);
    if (i == 0) { out[4202496] = 0.0f; out[20979713] = 0.0f; }
}

// ---------------- RoPE cos/sin table: tab[s*32+f] = (cos, sin) --------------
__global__ __launch_bounds__(256) void rope_tab_k(float2* __restrict__ tab) {
    const int i = blockIdx.x * 256 + threadIdx.x;   // 65536
    const int s = i >> 5, f = i & 31;
    float inv = powf(10000.0f, -(float)f * (1.0f / 32.0f));
    float sn, cs;
    sincosf((float)s * inv, &sn, &cs);
    tab[i] = make_float2(cs, sn);
}

// ---------------- ALL weights transpose + split, one dispatch ----------------
__global__ __launch_bounds__(256) void tsplit_all_k(const float* __restrict__ Wq,
                                                    const float* __restrict__ Wk,
                                                    const float* __restrict__ Wv,
                                                    const float* __restrict__ Wo,
                                                    const float* __restrict__ W1,
                                                    const float* __restrict__ W2,
                                                    ushort_t* __restrict__ wbuf) {
    __shared__ float T[32][33];
    const int bid = blockIdx.x;
    const int l = bid / 3072;
    const int r = bid % 3072;
    ushort_t* lb = wbuf + (size_t)l * 6291456;
    const float* W; ushort_t* Thi; ushort_t* Tlo; int K, N, ntn, rr;
    if (r < 768) {
        const int which = r >> 8; rr = r & 255;
        W = (which == 0 ? Wq : which == 1 ? Wk : Wv) + (size_t)l * 262144;
        Thi = lb + which * 262144; Tlo = lb + 786432 + which * 262144;
        K = 512; N = 512; ntn = 16;
    } else if (r < 1024) {
        rr = r - 768; W = Wo + (size_t)l * 262144;
        Thi = lb + 1572864; Tlo = lb + 1835008; K = 512; N = 512; ntn = 16;
    } else if (r < 2048) {
        rr = r - 1024; W = W1 + (size_t)l * 1048576;
        Thi = lb + 2097152; Tlo = lb + 3145728; K = 512; N = 2048; ntn = 64;
    } else {
        rr = r - 2048; W = W2 + (size_t)l * 1048576;
        Thi = lb + 4194304; Tlo = lb + 5242880; K = 2048; N = 512; ntn = 16;
    }
    const int n0 = (rr % ntn) * 32, k0 = (rr / ntn) * 32;
    const int tx = threadIdx.x & 31, ty = threadIdx.x >> 5;
    #pragma unroll
    for (int i = 0; i < 4; ++i)
        T[ty + 8 * i][tx] = W[(size_t)(k0 + ty + 8 * i) * N + n0 + tx];
    __syncthreads();
    #pragma unroll
    for (int i = 0; i < 4; ++i) {
        const int n = ty + 8 * i;
        float x = T[tx][n];
        ushort_t hi = f2bf(x);
        Thi[(size_t)(n0 + n) * K + k0 + tx] = hi;
        Tlo[(size_t)(n0 + n) * K + k0 + tx] = f2bf(x - bf2f(hi));
    }
}

// ---------------- RMSNorm -> hi/lo bf16 split --------------------------------
// Block->row remap (b&7)*1024 + (b>>3): writer-XCD == consumer-gemm-XCD.
__global__ __launch_bounds__(256) void rmsnorm_split_k(const float* __restrict__ x,
                                                       const float* __restrict__ w,
                                                       ushort_t* __restrict__ hhi,
                                                       ushort_t* __restrict__ hlo) {
    __shared__ float red[4];
    const int tid = threadIdx.x;
    const int b = blockIdx.x;
    const size_t row = (size_t)((b & 7) * 1024 + (b >> 3));
    const float* xr = x + row * DMODEL;
    float2 v = *(const float2*)(xr + tid * 2);
    float ss = v.x * v.x + v.y * v.y;
    #pragma unroll
    for (int off = 32; off; off >>= 1) ss += __shfl_down(ss, off);
    if ((tid & 63) == 0) red[tid >> 6] = ss;
    __syncthreads();
    float tot = red[0] + red[1] + red[2] + red[3];
    float rs = 1.0f / sqrtf(tot * (1.0f / 512.0f) + 1e-6f);
    float2 wv = *(const float2*)(w + tid * 2);
    float y0 = v.x * rs * wv.x, y1 = v.y * rs * wv.y;
    ushort_t h0 = f2bf(y0), h1 = f2bf(y1);
    ushort_t l0 = f2bf(y0 - bf2f(h0)), l1 = f2bf(y1 - bf2f(h1));
    *(unsigned*)(hhi + row * DMODEL + tid * 2) = ((unsigned)h1 << 16) | h0;
    *(unsigned*)(hlo + row * DMODEL + tid * 2) = ((unsigned)l1 << 16) | l0;
}

// ---------------- bf16x3 split MFMA GEMM (swizzled LDS, pipelined) ----------
// 1-D grid N/TN * 64 blocks, XCD-grouped (id&7 = XCD owns 8 bm rows).
// TN=128 (QKV/W1): 2-buffer, 1-ahead, __syncthreads per K-step.
// TN=64 (Wo/W2):  3-buffer, 2-ahead, counted vmcnt (T4): stage(t+2) issued
//   during compute(t), barrier waits vmcnt(LPS) so stage(t+1)'s 6 loads stay
//   in flight across the barrier. Raw s_barrier does NOT auto-drain vmcnt;
//   lgkmcnt(0) orders prior ds_reads before the 3rd buffer is overwritten.
template<int EPI, int TN>
__global__ __launch_bounds__(256) void gemm_s(const ushort_t* __restrict__ Ahi,
                                              const ushort_t* __restrict__ Alo,
                                              const ushort_t* __restrict__ Bhi,
                                              const ushort_t* __restrict__ Blo,
                                              int K, int N,
                                              float* __restrict__ C,
                                              const float* __restrict__ Cin,
                                              ushort_t* __restrict__ Chi,
                                              ushort_t* __restrict__ Clo,
                                              ushort_t* __restrict__ oqh,
                                              ushort_t* __restrict__ oql,
                                              ushort_t* __restrict__ okh,
                                              ushort_t* __restrict__ okl,
                                              ushort_t* __restrict__ ovh,
                                              const float2* __restrict__ rtab) {
    constexpr int MT = (TN == 128) ? 4 : 2;        // m-tiles per wave
    constexpr int NBUF = (TN == 64) ? 3 : 2;       // pipeline depth
    constexpr int LPS = (TN == 64) ? 6 : 8;        // gl_lds per thread per stage
    __shared__ __align__(16) ushort_t sAhi[NBUF][4096], sAlo[NBUF][4096];
    __shared__ __align__(16) ushort_t sBhi[NBUF][TN * 32], sBlo[NBUF][TN * 32];
    const int tid = threadIdx.x;
    const int lane = tid & 63, w = tid >> 6;
    const int wm = (TN == 128) ? (w >> 1) : w;
    const int wn = (TN == 128) ? (w & 1) : 0;
    const int nbn = N / TN;
    const int id = blockIdx.x;
    const int jj = id >> 3;
    const int bm = (id & 7) * 8 + jj / nbn;        // XCD-grouped bm
    const int bn = jj % nbn;
    const int sm = lane >> 2;                       // staging row in 16-chunk
    const int sk = ((lane & 3) ^ ((sm >> 1) & 3)) * 8;  // swizzled global quad
    const int fr = lane & 15;
    const int fq = lane >> 4;
    const int fko = (fq ^ ((fr >> 1) & 3)) * 8;     // swizzled frag k-offset

    auto stage = [&](int buf, int kt) {
        #pragma unroll
        for (int j = 0; j < 2; ++j) {              // A: 8 chunks x 16 rows
            const int chunk = w * 2 + j;
            const int mr = chunk * 16 + sm;
            const size_t ga = (size_t)(bm * 128 + mr) * K + kt + sk;
            gl_lds16(Ahi + ga, &sAhi[buf][chunk * 512]);
            gl_lds16(Alo + ga, &sAlo[buf][chunk * 512]);
        }
        #pragma unroll
        for (int j = 0; j < TN / 64; ++j) {        // B: TN/16 chunks
            const int chunk = w * (TN / 64) + j;
            const int mr = chunk * 16 + sm;
            const size_t gb = (size_t)(bn * TN + mr) * K + kt + sk;
            gl_lds16(Bhi + gb, &sBhi[buf][chunk * 512]);
            gl_lds16(Blo + gb, &sBlo[buf][chunk * 512]);
        }
    };

    float4_t acc[MT][4] = {};

    if (NBUF == 3) {
        stage(0, 0);
        if (32 < K) stage(1, 32);
    } else {
        stage(0, 0);
    }
    int cur = 0;
    for (int kt = 0; kt < K; kt += 32) {
        if (NBUF == 2) {
            __syncthreads();                       // buf[cur] ready; prior reads done
            if (kt + 32 < K) stage(cur ^ 1, kt + 32);
        } else {
            // retire stage(t) only; stage(t+1) (6 loads) stays in flight
            if (kt + 32 < K)
                asm volatile("s_waitcnt vmcnt(%0) lgkmcnt(0)" :: "i"(LPS) : "memory");
            else
                asm volatile("s_waitcnt vmcnt(0) lgkmcnt(0)" ::: "memory");
            __builtin_amdgcn_s_barrier();
            if (kt + 64 < K) stage((cur + 2) % 3, kt + 64);
        }
        short8_t ah[MT], al[MT], bh[4], bl[4];
        #pragma unroll
        for (int t = 0; t < MT; ++t) {
            const int ao = (wm * (MT * 16) + t * 16 + fr) * 32 + fko;
            ah[t] = *(const short8_t*)&sAhi[cur][ao];
            al[t] = *(const short8_t*)&sAlo[cur][ao];
        }
        #pragma unroll
        for (int t = 0; t < 4; ++t) {
            const int bo = (wn * 64 + t * 16 + fr) * 32 + fko;
            bh[t] = *(const short8_t*)&sBhi[cur][bo];
            bl[t] = *(const short8_t*)&sBlo[cur][bo];
        }
        #pragma unroll
        for (int tm = 0; tm < MT; ++tm)
            #pragma unroll
            for (int tn = 0; tn < 4; ++tn) {
                acc[tm][tn] = MFMA16(ah[tm], bh[tn], acc[tm][tn]);
                acc[tm][tn] = MFMA16(al[tm], bh[tn], acc[tm][tn]);
                acc[tm][tn] = MFMA16(ah[tm], bl[tn], acc[tm][tn]);
            }
        cur = (cur + 1) % NBUF;
    }

    // epilogue: C/D layout col = lane&15, row = (lane>>4)*4 + reg  [m89/m91]
    if (EPI == 0) {
        const int cb = bn * 128 + wn * 64;         // one head per wave-half
        const int mat = cb >> 9;                   // 0=q 1=k 2=v
        const int hh = (cb >> 6) & 7;
        #pragma unroll
        for (int tm = 0; tm < MT; ++tm) {
            #pragma unroll
            for (int r = 0; r < 4; ++r) {
                const int mg = bm * 128 + wm * (MT * 16) + tm * 16 + fq * 4 + r;
                const int b = mg >> 11, s = mg & 2047;
                const int bhh = b * NHEAD + hh;
                if (mat < 2) {
                    ushort_t* dhi = (mat == 0) ? oqh : okh;
                    ushort_t* dlo = (mat == 0) ? oql : okl;
                    const size_t base = ((size_t)bhh * S_LEN + s) * DH;
                    #pragma unroll
                    for (int tn = 0; tn < 2; ++tn) {
                        const int d1 = tn * 16 + fr;
                        const float v1 = acc[tm][tn][r], v2 = acc[tm][tn + 2][r];
                        const float2 t = rtab[s * 32 + d1];
                        float r1 = v1 * t.x - v2 * t.y;
                        float r2 = v1 * t.y + v2 * t.x;
                        if (mat == 0) { r1 *= 0.125f; r2 *= 0.125f; } // fold 1/sqrt(Dh)
                        ushort_t h1 = f2bf(r1), h2 = f2bf(r2);
                        dhi[base + d1]      = h1;
                        dlo[base + d1]      = f2bf(r1 - bf2f(h1));
                        dhi[base + d1 + 32] = h2;
                        dlo[base + d1 + 32] = f2bf(r2 - bf2f(h2));
                    }
                } else {
                    #pragma unroll
                    for (int tn = 0; tn < 4; ++tn) {
                        const int d = tn * 16 + fr;
                        const size_t off = ((size_t)bhh * DH + d) * S_LEN + s;
                        ovh[off] = f2bf(acc[tm][tn][r]);
                    }
                }
            }
        }
    } else {
        #pragma unroll
        for (int tm = 0; tm < MT; ++tm) {
            #pragma unroll
            for (int tn = 0; tn < 4; ++tn) {
                const int cb = bn * TN + wn * 64 + tn * 16;
                #pragma unroll
                for (int r = 0; r < 4; ++r) {
                    const int mg = bm * 128 + wm * (MT * 16) + tm * 16 + fq * 4 + r;
                    const float val = acc[tm][tn][r];
                    const size_t off = (size_t)mg * N + cb + fr;
                    if (EPI == 1) {
                        C[off] = Cin[off] + val;
                    } else {
                        const float g = gelu_f(val);
                        const ushort_t hi = f2bf(g);
                        Chi[off] = hi;
                        Clo[off] = f2bf(g - bf2f(hi));
                    }
                }
            }
        }
    }
}

// ---------------- MFMA causal flash attention (swizzled LDS) -----------------
// 1-D grid 1024: bh = blockIdx&31 (XCD-pinned K/V: id&7 = bh&7), qt heavy-
// first (31 - id>>5). 40KB LDS -> 4 blocks/CU: co-resident blocks fill both
// pipes' idle slots (m114 inter-block overlap).
// Vh double-buffered (staged at top of step t for t+1); Kh AND Kl SINGLE-
// buffered: both are QK-phase-only reads, so they're staged at the mid-step
// barrier after softmax (all QK(t) reads retired by then) and drained by the
// next top barrier before QK(t+1) reads them.
// Softmax reductions use DPP (VALU) instead of shfl_xor (ds_bpermute).
__global__ __launch_bounds__(256) void attn_k(const ushort_t* __restrict__ qhi,
                                              const ushort_t* __restrict__ qlo,
                                              const ushort_t* __restrict__ khi,
                                              const ushort_t* __restrict__ klo,
                                              const ushort_t* __restrict__ vthi,
                                              ushort_t* __restrict__ Ohi,
                                              ushort_t* __restrict__ Olo) {
    __shared__ __align__(16) ushort_t sVh[2][4096];
    __shared__ __align__(16) ushort_t sKh[4096], sKl[4096], sPh[4096];
    const int tid = threadIdx.x, lane = tid & 63, w = tid >> 6;
    const int fr = lane & 15, fq = lane >> 4;
    const int fko = (fq ^ ((fr >> 1) & 3)) * 8;     // swizzled frag k-offset
    const int bidx = blockIdx.x;
    const int bh = bidx & 31;
    const int qt = 31 - (bidx >> 5);                // heavy blocks dispatch first

    short8_t qfh[2], qfl[2];
    {
        const size_t base = ((size_t)bh * S_LEN + qt * 64 + w * 16 + fr) * DH + fq * 8;
        qfh[0] = *(const short8_t*)(qhi + base);
        qfh[1] = *(const short8_t*)(qhi + base + 32);
        qfl[0] = *(const short8_t*)(qlo + base);
        qfl[1] = *(const short8_t*)(qlo + base + 32);
    }

    float m_r[4], l_r[4];
    float4_t oacc[4] = {};
    #pragma unroll
    for (int r = 0; r < 4; ++r) { m_r[r] = -INFINITY; l_r[r] = 0.0f; }

    // prologue: stage everything for step 0
    stage_tile(khi + (size_t)bh * S_LEN * DH, 64, sKh, w, lane);
    stage_tile(klo + (size_t)bh * S_LEN * DH, 64, sKl, w, lane);
    stage_tile(vthi + (size_t)bh * DH * S_LEN, S_LEN, sVh[0], w, lane);
    int cur = 0;

    for (int kt = 0; kt <= qt; ++kt) {
        const bool diag = (kt == qt);
        __syncthreads();        // vmcnt(0): sVh[cur]+sKh+sKl visible; prior reads done
        if (kt < qt) {          // prefetch Vh(t+1); Kh/Kl(t+1) staged at mid-barrier
            const size_t vo = (size_t)bh * DH * S_LEN + (kt + 1) * 64;
            stage_tile(vthi + vo, S_LEN, sVh[cur ^ 1], w, lane);
        }

        float4_t sacc[4] = {};
        __builtin_amdgcn_s_setprio(1);
        #pragma unroll
        for (int kk = 0; kk < 2; ++kk) {
            #pragma unroll
            for (int n = 0; n < 4; ++n) {
                const int bb = kk * 2048 + (n * 16 + fr) * 32 + fko;
                short8_t kh2 = *(const short8_t*)&sKh[bb];
                short8_t kl2 = *(const short8_t*)&sKl[bb];
                sacc[n] = MFMA16(qfh[kk], kh2, sacc[n]);
                sacc[n] = MFMA16(qfl[kk], kh2, sacc[n]);
                sacc[n] = MFMA16(qfh[kk], kl2, sacc[n]);
            }
        }
        __builtin_amdgcn_s_setprio(0);

        #pragma unroll
        for (int r = 0; r < 4; ++r) {
            const int qrow = w * 16 + fq * 4 + r;
            const int psw = (qrow >> 1) & 3;       // P write swizzle
            float sv[4], mx = -INFINITY;
            #pragma unroll
            for (int n = 0; n < 4; ++n) {
                sv[n] = sacc[n][r];
                if (diag && (n * 16 + fr) > qrow) sv[n] = -1e30f;
                mx = fmaxf(mx, sv[n]);
            }
            mx = dpp_max16(mx);
            const float mn = fmaxf(m_r[r], mx);
            const float alp = __expf(m_r[r] - mn);
            m_r[r] = mn;
            float ls = 0.0f;
            #pragma unroll
            for (int n = 0; n < 4; ++n) {
                const float pv = __expf(sv[n] - mn);
                const int c0 = (n & 1) * 16 + fr;
                const int idx = (n >> 1) * 2048 + qrow * 32 + ((c0 >> 3) ^ psw) * 8 + (c0 & 7);
                sPh[idx] = f2bf(pv);
                ls += pv;
            }
            ls = dpp_sum16(ls);
            l_r[r] = alp * l_r[r] + ls;
            #pragma unroll
            for (int n = 0; n < 4; ++n) oacc[n][r] *= alp;
        }

        if (kt < qt) {
            __syncthreads();    // all waves' sKh/sKl QK-reads retired; safe to overwrite
            const size_t ko = ((size_t)bh * S_LEN + (kt + 1) * 64) * DH;
            stage_tile(khi + ko, 64, sKh, w, lane);
            stage_tile(klo + ko, 64, sKl, w, lane);
        }

        __builtin_amdgcn_s_setprio(1);
        #pragma unroll
        for (int kkj = 0; kkj < 2; ++kkj) {
            short8_t ph = *(const short8_t*)&sPh[kkj * 2048 + (w * 16 + fr) * 32 + fko];
            #pragma unroll
            for (int n = 0; n < 4; ++n) {
                short8_t vh = *(const short8_t*)&sVh[cur][kkj * 2048 + (n * 16 + fr) * 32 + fko];
                oacc[n] = MFMA16(ph, vh, oacc[n]);
            }
        }
        __builtin_amdgcn_s_setprio(0);
        cur ^= 1;
    }

    const int b = bh >> 3, hh = bh & 7;
    #pragma unroll
    for (int r = 0; r < 4; ++r) {
        const float inv_l = 1.0f / l_r[r];
        const int s = qt * 64 + w * 16 + fq * 4 + r;
        const size_t base = ((size_t)b * S_LEN + s) * DMODEL + hh * DH;
        #pragma unroll
        for (int n = 0; n < 4; ++n) {
            const float y = oacc[n][r] * inv_l;
            const ushort_t h = f2bf(y);
            Ohi[base + n * 16 + fr] = h;
            Olo[base + n * 16 + fr] = f2bf(y - bf2f(h));
        }
    }
}

// ---------------- head: logits -> sigmoid -> probs (no atomics) -------------
__global__ __launch_bounds__(256) void head_k(const float* __restrict__ x,
                                              const float* __restrict__ w,
                                              const float* __restrict__ b,
                                              float* __restrict__ probs) {
    const int tid = threadIdx.x;
    const int lane = tid & 63;
    const size_t row = (size_t)blockIdx.x * 4 + (tid >> 6);
    const float* xr = x + row * DMODEL;
    float acc = 0.0f;
    #pragma unroll
    for (int i = 0; i < 8; ++i) acc += xr[lane + i * 64] * w[lane + i * 64];
    #pragma unroll
    for (int off = 32; off; off >>= 1) acc += __shfl_down(acc, off);
    if (lane == 0)
        probs[row] = 1.0f / (1.0f + expf(-(acc + b[0])));
}

// ---------------- chunk id scan (binary lifting) + loss reduction ------------
__global__ __launch_bounds__(256) void chunk_k(const float* __restrict__ probs,
                                               int* __restrict__ ids,
                                               float* __restrict__ avg_out,
                                               float* __restrict__ loss_out) {
    __shared__ ushort_t nxA[2052], nxB[2052];
    __shared__ ushort_t lift[10][2052];
    __shared__ float lred[4];
    __shared__ int anyf;
    const int b = blockIdx.x, tid = threadIdx.x;
    const float* pr = probs + (size_t)b * S_LEN;
    if (tid == 0) anyf = 0;
    __syncthreads();
    int loc = 0;
    float lsum = 0.0f;
    for (int t = tid; t < S_LEN; t += 256) {
        const float p = pr[t];
        loc |= (p > 0.5f) ? 1 : 0;
        lsum += p;
    }
    if (loc) atomicOr(&anyf, 1);
    #pragma unroll
    for (int off = 32; off; off >>= 1) lsum += __shfl_down(lsum, off);
    if ((tid & 63) == 0) lred[tid >> 6] = lsum;
    __syncthreads();
    if (tid == 0)
        atomicAdd(loss_out, (lred[0] + lred[1] + lred[2] + lred[3]) * 0.25f);
    const int any = anyf;
    for (int i = tid; i <= S_LEN; i += 256) {
        const bool he = any ? (i >= 1 && pr[i - 1] > 0.5f) : (i == S_LEN - 1);
        nxA[i] = he ? (ushort_t)i : (ushort_t)(S_LEN + 1);
    }
    __syncthreads();
    ushort_t* src = nxA;
    ushort_t* dst = nxB;
    for (int d = 1; d <= 2048; d <<= 1) {
        for (int i = tid; i <= S_LEN; i += 256) {
            ushort_t v = src[i];
            if (i + d <= S_LEN) { ushort_t u2 = src[i + d]; v = u2 < v ? u2 : v; }
            dst[i] = v;
        }
        __syncthreads();
        ushort_t* tmp = src; src = dst; dst = tmp;
    }
    for (int t = tid; t < S_LEN; t += 256) {
        int cap = t + 16; if (cap > S_LEN) cap = S_LEN;
        int e = src[t + 1];
        if (e > cap) e = cap;
        if (e - t < 3) { e = t + 3; if (e > S_LEN) e = S_LEN; }
        lift[0][t] = (ushort_t)e;
    }
    if (tid == 0) lift[0][S_LEN] = (ushort_t)S_LEN;
    __syncthreads();
    for (int j = 1; j < 10; ++j) {
        for (int t = tid; t <= S_LEN; t += 256)
            lift[j][t] = lift[j - 1][lift[j - 1][t]];
        __syncthreads();
    }
    for (int t = tid; t < S_LEN; t += 256) {
        int pos = 0, cid = 0;
        #pragma unroll
        for (int j = 9; j >= 0; --j) {
            const int p2 = lift[j][pos];
            if (p2 <= t) { pos = p2; cid += (1 << j); }
        }
        ids[(size_t)b * S_LEN + t] = cid;
        if (t == S_LEN - 1) atomicAdd(avg_out, 512.0f / (float)(cid + 1));
    }
}

// ---------------- masks ------------------------------------------------------
// Row base is odd (4-byte aligned only), but mr+1 is 8B-aligned: elements 0
// and 2047 stored scalar, [1..2046] as 1023 aligned float2 pairs.
__global__ __launch_bounds__(256) void masks_k(const int* __restrict__ ids,
                                               float* __restrict__ mask) {
    const int bq = blockIdx.x;
    const int b = bq >> 11;
    const int myid = ids[bq];
    const int* idr = ids + (size_t)b * S_LEN;
    float* mr = mask + (size_t)bq * S_LEN;
    if (threadIdx.x == 0) {
        mr[0] = (idr[0] == myid) ? 1.0f : 0.0f;
        mr[2047] = (idr[2047] == myid) ? 1.0f : 0.0f;
    }
    float2* m2 = (float2*)(mr + 1);
    for (int k = threadIdx.x; k < 1023; k += 256) {
        const int i0 = idr[1 + 2 * k], i1 = idr[2 + 2 * k];
        m2[k] = make_float2(i0 == myid ? 1.0f : 0.0f, i1 == myid ? 1.0f : 0.0f);
    }
}

extern "C" void kernel_launch(void* const* d_in, const int* in_sizes, int n_in,
                              void* d_out, int out_size, void* d_ws, size_t ws_size,
                              hipStream_t stream) {
    (void)in_sizes; (void)n_in; (void)out_size; (void)ws_size;
    const float* x      = (const float*)d_in[0];
    const int*   x_ids  = (const int*)d_in[1];
    const float* ln1    = (const float*)d_in[2];
    const float* Wq     = (const float*)d_in[3];
    const float* Wk     = (const float*)d_in[4];
    const float* Wv     = (const float*)d_in[5];
    const float* Wo     = (const float*)d_in[6];
    const float* ln2    = (const float*)d_in[7];
    const float* W1     = (const float*)d_in[8];
    const float* W2     = (const float*)d_in[9];
    const float* head_w = (const float*)d_in[10];
    const float* head_b = (const float*)d_in[11];

    float* out = (float*)d_out;
    ushort_t* u = (ushort_t*)d_ws;
    ushort_t* qh   = u;                 // [32 bh][2048 s][64 d] roped q (x 1/8) hi
    ushort_t* ql   = u + 4194304;
    ushort_t* kh   = u + 8388608;       // roped k
    ushort_t* kl   = u + 12582912;
    ushort_t* vth  = u + 16777216;      // v transposed hi [32 bh][64 d][2048 s]
    ushort_t* ohi  = u + 25165824;      // attn out [8192][512]
    ushort_t* olo  = u + 29360128;
    ushort_t* hhi  = u + 33554432;      // rmsnorm out [8192][512]
    ushort_t* hlo  = u + 37748736;
    ushort_t* ffhi = u;                 // [8192][2048]; overlays q..k (dead after attn)
    ushort_t* fflo = u + 16777216;      // overlays vt..o (dead after Wo gemm)
    float*    probs = (float*)(u + 41943040);
    int*      ids   = (int*)(u + 41943040 + 16384);
    // weight-split (both layers) + rope table in out's mask region:
    ushort_t* wbuf     = (ushort_t*)(out + 4202512);   // 16B-aligned
    float2*   rope_tab = (float2*)(wbuf + 12582912);   // [2048][32] (cos,sin)
    float* xbuf = out;

    copy_init_k<<<8, 256, 0, stream>>>(x_ids, out);
    rope_tab_k<<<256, 256, 0, stream>>>(rope_tab);
    tsplit_all_k<<<6144, 256, 0, stream>>>(Wq, Wk, Wv, Wo, W1, W2, wbuf);

    for (int l = 0; l < 2; ++l) {
        ushort_t* lb = wbuf + (size_t)l * 6291456;
        ushort_t* qkvT_hi = lb;
        ushort_t* qkvT_lo = lb + 786432;
        ushort_t* woT_hi  = lb + 1572864;
        ushort_t* woT_lo  = lb + 1835008;
        ushort_t* w1T_hi  = lb + 2097152;
        ushort_t* w1T_lo  = lb + 3145728;
        ushort_t* w2T_hi  = lb + 4194304;
        ushort_t* w2T_lo  = lb + 5242880;
        // layer 0 reads the residual stream straight from the input buffer;
        // the Wo-gemm (full M x N coverage) then writes all of xbuf.
        const float* xin = (l == 0) ? x : xbuf;

        rmsnorm_split_k<<<8192, 256, 0, stream>>>(xin, ln1 + l * DMODEL, hhi, hlo);
        gemm_s<0, 128><<<768, 256, 0, stream>>>(hhi, hlo, qkvT_hi, qkvT_lo, 512, 1536,
                                                nullptr, nullptr, nullptr, nullptr,
                                                qh, ql, kh, kl, vth, rope_tab);
        attn_k<<<1024, 256, 0, stream>>>(qh, ql, kh, kl, vth, ohi, olo);
        gemm_s<1, 64><<<512, 256, 0, stream>>>(ohi, olo, woT_hi, woT_lo, 512, 512,
                                               xbuf, xin, nullptr, nullptr,
                                               nullptr, nullptr, nullptr, nullptr, nullptr, nullptr);
        rmsnorm_split_k<<<8192, 256, 0, stream>>>(xbuf, ln2 + l * DMODEL, hhi, hlo);
        gemm_s<2, 128><<<1024, 256, 0, stream>>>(hhi, hlo, w1T_hi, w1T_lo, 512, 2048,
                                                 nullptr, nullptr, ffhi, fflo,
                                                 nullptr, nullptr, nullptr, nullptr, nullptr, nullptr);
        gemm_s<1, 64><<<512, 256, 0, stream>>>(ffhi, fflo, w2T_hi, w2T_lo, 2048, 512,
                                               xbuf, xbuf, nullptr, nullptr,
                                               nullptr, nullptr, nullptr, nullptr, nullptr, nullptr);
    }

    head_k<<<2048, 256, 0, stream>>>(xbuf, head_w, head_b, probs);
    chunk_k<<<4, 256, 0, stream>>>(probs, ids, out + 4202496, out + 20979713);
    masks_k<<<8192, 256, 0, stream>>>(ids, out + 4202497);
}